// Round 1
// baseline (92.069 us; speedup 1.0000x reference)
//
#include <hip/hip_runtime.h>

// Problem constants
#define TT   1024            // time steps
#define DD   1280            // feature dim
#define WW   320             // DD / POOL
#define CC   20              // channels
#define HALF 10
#define TW   (TT*WW)         // 327680
#define LIN  (CC*WW)         // 6400  (GEMM K)
#define OUTD 80              // GEMM N
#define NSPLIT 16
#define KCHUNK (LIN/NSPLIT)  // 400
#define BK   80
#define NTILE (KCHUNK/BK)    // 5
#define BM   32

// ---------------- Kernel 1: MaxPool2d((1,4)) ----------------
__global__ __launch_bounds__(256) void k_pool(const float* __restrict__ f,
                                              float* __restrict__ x) {
    int idx = blockIdx.x * 256 + threadIdx.x;          // over TW, exact
    float4 v = reinterpret_cast<const float4*>(f)[idx];
    x[idx] = fmaxf(fmaxf(v.x, v.y), fmaxf(v.z, v.w));
}

// ---------------- Kernel 2: 3x3 windowed attention, all 20 channels ----------------
__global__ __launch_bounds__(256) void k_attn(const float* __restrict__ x,
                                              const float* __restrict__ wq,
                                              const float* __restrict__ wk,
                                              const float* __restrict__ wv,
                                              const float* __restrict__ rh,
                                              const float* __restrict__ rw,
                                              float* __restrict__ att) {
    int idx = blockIdx.x * 256 + threadIdx.x;          // over TW
    int t = idx / WW, w = idx % WW;

    float xn[9];
    #pragma unroll
    for (int dt = -1; dt <= 1; ++dt) {
        #pragma unroll
        for (int dw = -1; dw <= 1; ++dw) {
            int tt2 = t + dt, ww2 = w + dw;
            bool ok = (tt2 >= 0) & (tt2 < TT) & (ww2 >= 0) & (ww2 < WW);
            xn[(dt+1)*3 + (dw+1)] = ok ? x[tt2*WW + ww2] : 0.0f;
        }
    }
    float xc = xn[4];

    for (int c = 0; c < CC; ++c) {
        float q  = wq[c] * xc;
        float kk = wk[c];
        float vv = wv[c];
        float r0, r1, r2;
        bool ish = (c < HALF);
        if (ish) { r0 = rh[c*3+0]; r1 = rh[c*3+1]; r2 = rh[c*3+2]; }
        else     { int cc = c - HALF; r0 = rw[cc*3+0]; r1 = rw[cc*3+1]; r2 = rw[cc*3+2]; }

        float relv[9];
        if (ish) {
            relv[0]=r0; relv[1]=r0; relv[2]=r0;
            relv[3]=r1; relv[4]=r1; relv[5]=r1;
            relv[6]=r2; relv[7]=r2; relv[8]=r2;
        } else {
            relv[0]=r0; relv[1]=r1; relv[2]=r2;
            relv[3]=r0; relv[4]=r1; relv[5]=r2;
            relv[6]=r0; relv[7]=r1; relv[8]=r2;
        }

        float qk = q * kk;
        float s[9];
        #pragma unroll
        for (int i = 0; i < 9; ++i) s[i] = qk * xn[i] + q * relv[i];

        float m = s[0];
        #pragma unroll
        for (int i = 1; i < 9; ++i) m = fmaxf(m, s[i]);

        float den = 0.f, num = 0.f;
        #pragma unroll
        for (int i = 0; i < 9; ++i) {
            float p = __expf(s[i] - m);
            den += p;
            num += p * xn[i];
        }
        float o = vv * __fdividef(num, den);
        att[c*TW + idx] = fmaxf(o, 0.0f);
    }
}

// ---------------- Kernel 3: split-K GEMM  [1024 x 6400] * [6400 x 80]^T ----------------
__global__ __launch_bounds__(256) void k_gemm(const float* __restrict__ flat,
                                              const float* __restrict__ dw,
                                              float* __restrict__ part) {
    __shared__ float As[BM][BK+1];      // [32][81]
    __shared__ float Bs[BK][OUTD+1];    // [80][81]
    int tid   = threadIdx.x;
    int r0    = blockIdx.x * BM;
    int split = blockIdx.y;
    int kbase = split * KCHUNK;
    int ty = tid / 8;      // row 0..31
    int tx = tid % 8;      // col group: cols tx*10 .. tx*10+9

    float acc[10];
    #pragma unroll
    for (int i = 0; i < 10; ++i) acc[i] = 0.f;

    for (int tile = 0; tile < NTILE; ++tile) {
        int k0 = kbase + tile * BK;
        // stage A: 32x80 = 2560 elems
        for (int i = tid; i < BM*BK; i += 256) {
            int row = i / BK, kk = i % BK;
            As[row][kk] = flat[(size_t)(r0 + row) * LIN + k0 + kk];
        }
        // stage B: 80x80 = 6400 elems (read coalesced along K, store transposed)
        for (int i = tid; i < BK*OUTD; i += 256) {
            int o = i / BK, kk = i % BK;
            Bs[kk][o] = dw[(size_t)o * LIN + k0 + kk];
        }
        __syncthreads();
        #pragma unroll 8
        for (int kk = 0; kk < BK; ++kk) {
            float a = As[ty][kk];
            #pragma unroll
            for (int c2 = 0; c2 < 10; ++c2)
                acc[c2] += a * Bs[kk][tx*10 + c2];
        }
        __syncthreads();
    }
    float* p = part + (size_t)split * TT * OUTD + (size_t)(r0 + ty) * OUTD + tx*10;
    #pragma unroll
    for (int c2 = 0; c2 < 10; ++c2) p[c2] = acc[c2];
}

// ---------------- Kernel 4: split-K reduce + bias ----------------
__global__ __launch_bounds__(256) void k_reduce(const float* __restrict__ part,
                                                const float* __restrict__ bias,
                                                float* __restrict__ out) {
    int idx = blockIdx.x * 256 + threadIdx.x;   // over TT*OUTD = 81920, exact
    int o = idx % OUTD;
    float s = bias[o];
    #pragma unroll
    for (int sp = 0; sp < NSPLIT; ++sp) s += part[(size_t)sp * TT * OUTD + idx];
    out[idx] = s;
}

extern "C" void kernel_launch(void* const* d_in, const int* in_sizes, int n_in,
                              void* d_out, int out_size, void* d_ws, size_t ws_size,
                              hipStream_t stream) {
    const float* feature = (const float*)d_in[0];
    const float* wq      = (const float*)d_in[1];
    const float* wk      = (const float*)d_in[2];
    const float* wv      = (const float*)d_in[3];
    const float* rel_h   = (const float*)d_in[4];
    const float* rel_w   = (const float*)d_in[5];
    const float* dense_w = (const float*)d_in[6];
    const float* dense_b = (const float*)d_in[7];
    float* out = (float*)d_out;

    float* ws   = (float*)d_ws;
    float* x    = ws;                       // TW floats           (1.31 MB)
    float* att  = ws + TW;                  // CC*TW floats        (26.2 MB)
    float* part = att + (size_t)CC * TW;    // NSPLIT*TT*OUTD      (5.24 MB)

    k_pool  <<<TW/256, 256, 0, stream>>>(feature, x);
    k_attn  <<<TW/256, 256, 0, stream>>>(x, wq, wk, wv, rel_h, rel_w, att);
    k_gemm  <<<dim3(TT/BM, NSPLIT), 256, 0, stream>>>(att, dense_w, part);
    k_reduce<<<(TT*OUTD)/256, 256, 0, stream>>>(part, dense_b, out);
}

// Round 2
// 67.551 us; speedup vs baseline: 1.3630x; 1.3630x over previous
//
#include <hip/hip_runtime.h>
#include <hip/hip_bf16.h>

// Problem constants
#define TT   1024            // time steps
#define DD   1280            // feature dim
#define WW   320             // DD / POOL
#define CC   20              // channels
#define HALF 10
#define TW   (TT*WW)         // 327680
#define LIN  (CC*WW)         // 6400  (GEMM K)
#define OUTD 80              // GEMM N
#define NSPLIT 20
#define KCHUNK (LIN/NSPLIT)  // 320
#define KSTEPS (KCHUNK/32)   // 10
#define LOG2E 1.4426950408889634f

typedef __attribute__((ext_vector_type(4))) float f32x4;
typedef __attribute__((ext_vector_type(8))) short bf16x8;

// ---------------- Kernel 1: MaxPool2d((1,4)) ----------------
__global__ __launch_bounds__(256) void k_pool(const float* __restrict__ f,
                                              float* __restrict__ x) {
    int idx = blockIdx.x * 256 + threadIdx.x;          // over TW, exact
    float4 v = reinterpret_cast<const float4*>(f)[idx];
    x[idx] = fmaxf(fmaxf(v.x, v.y), fmaxf(v.z, v.w));
}

// ---------------- Kernel 2: dense_w fp32 -> bf16 ----------------
__global__ __launch_bounds__(256) void k_cvt(const float* __restrict__ dw,
                                             ushort* __restrict__ dwb) {
    int i = (blockIdx.x * 256 + threadIdx.x) * 8;      // 512000/8 = 64000 threads, 250 blocks
    float4 a = reinterpret_cast<const float4*>(dw + i)[0];
    float4 b = reinterpret_cast<const float4*>(dw + i)[1];
    ushort r[8];
    float v[8] = {a.x, a.y, a.z, a.w, b.x, b.y, b.z, b.w};
    #pragma unroll
    for (int j = 0; j < 8; ++j) {
        __hip_bfloat16 h = __float2bfloat16(v[j]);
        r[j] = *reinterpret_cast<ushort*>(&h);
    }
    reinterpret_cast<ushort4*>(dwb + i)[0] = make_ushort4(r[0], r[1], r[2], r[3]);
    reinterpret_cast<ushort4*>(dwb + i)[1] = make_ushort4(r[4], r[5], r[6], r[7]);
}

// ---------------- Kernel 3: 3x3 windowed attention -> bf16, 4 w-positions/thread ----------------
__global__ __launch_bounds__(256) void k_attn(const float* __restrict__ x,
                                              const float* __restrict__ wq,
                                              const float* __restrict__ wk,
                                              const float* __restrict__ wv,
                                              const float* __restrict__ rh,
                                              const float* __restrict__ rw,
                                              ushort* __restrict__ att) {
    __shared__ float s_wqk[CC], s_wr[CC][3], s_wv[CC];
    if (threadIdx.x < CC) {
        int c = threadIdx.x;
        float wqc = wq[c];
        s_wqk[c] = wqc * wk[c] * LOG2E;
        s_wv[c]  = wv[c];
        const float* rp = (c < HALF) ? (rh + c * 3) : (rw + (c - HALF) * 3);
        s_wr[c][0] = wqc * rp[0] * LOG2E;
        s_wr[c][1] = wqc * rp[1] * LOG2E;
        s_wr[c][2] = wqc * rp[2] * LOG2E;
    }
    __syncthreads();

    int idx = blockIdx.x * 256 + threadIdx.x;          // 0..81919
    int t  = idx / (WW / 4);
    int w0 = (idx % (WW / 4)) * 4;

    // load x[t-1..t+1][w0-1..w0+4]
    float xr[3][6];
    #pragma unroll
    for (int dt = 0; dt < 3; ++dt) {
        int tt2 = t + dt - 1;
        bool rok = (tt2 >= 0) & (tt2 < TT);
        #pragma unroll
        for (int dw = 0; dw < 6; ++dw) {
            int ww2 = w0 + dw - 1;
            bool ok = rok & (ww2 >= 0) & (ww2 < WW);
            xr[dt][dw] = ok ? x[tt2 * WW + ww2] : 0.0f;
        }
    }

    #pragma unroll 2
    for (int c = 0; c < CC; ++c) {
        float wqk = s_wqk[c];
        float b0c = s_wr[c][0], b1c = s_wr[c][1], b2c = s_wr[c][2];
        float vv  = s_wv[c];
        bool ish = (c < HALF);
        ushort res[4];
        #pragma unroll
        for (int p = 0; p < 4; ++p) {
            float xc = xr[1][p + 1];
            float a  = wqk * xc;
            float bb[3] = {xc * b0c, xc * b1c, xc * b2c};
            float s[9];
            #pragma unroll
            for (int dt = 0; dt < 3; ++dt)
                #pragma unroll
                for (int dw = 0; dw < 3; ++dw)
                    s[dt * 3 + dw] = fmaf(a, xr[dt][p + dw], ish ? bb[dt] : bb[dw]);
            float m = fmaxf(fmaxf(fmaxf(s[0], s[1]), fmaxf(s[2], s[3])),
                            fmaxf(fmaxf(s[4], s[5]), fmaxf(fmaxf(s[6], s[7]), s[8])));
            float den = 0.f, num = 0.f;
            #pragma unroll
            for (int dt = 0; dt < 3; ++dt)
                #pragma unroll
                for (int dw = 0; dw < 3; ++dw) {
                    float pp = exp2f(s[dt * 3 + dw] - m);
                    den += pp;
                    num = fmaf(pp, xr[dt][p + dw], num);
                }
            float o = fmaxf(vv * __fdividef(num, den), 0.0f);
            __hip_bfloat16 h = __float2bfloat16(o);
            res[p] = *reinterpret_cast<ushort*>(&h);
        }
        reinterpret_cast<ushort4*>(att + (size_t)c * TW + t * WW + w0)[0] =
            make_ushort4(res[0], res[1], res[2], res[3]);
    }
}

// ---------------- Kernel 4: bf16 MFMA split-K GEMM  [1024 x 6400] * [6400 x 80]^T ----------------
// one wave per block: 16 rows x 80 cols, KCHUNK of K
__global__ __launch_bounds__(64) void k_gemm(const ushort* __restrict__ A,
                                             const ushort* __restrict__ B,
                                             float* __restrict__ part) {
    int lane = threadIdx.x;
    int mt = blockIdx.x;        // 0..63  (M tile of 16 rows)
    int sp = blockIdx.y;        // 0..NSPLIT-1
    int r16 = lane & 15;        // A row / B col / C col
    int kg  = lane >> 4;        // k-group 0..3

    const ushort* ap = A + (size_t)(mt * 16 + r16) * LIN + sp * KCHUNK + kg * 8;
    const ushort* bp = B + (size_t)r16 * LIN + sp * KCHUNK + kg * 8;

    f32x4 acc[5] = {};
    for (int ks = 0; ks < KSTEPS; ++ks) {
        bf16x8 af = *reinterpret_cast<const bf16x8*>(ap);
        #pragma unroll
        for (int j = 0; j < 5; ++j) {
            bf16x8 bfr = *reinterpret_cast<const bf16x8*>(bp + (size_t)j * 16 * LIN);
            acc[j] = __builtin_amdgcn_mfma_f32_16x16x32_bf16(af, bfr, acc[j], 0, 0, 0);
        }
        ap += 32;
        bp += 32;
    }

    // C/D layout: col = lane&15, row = (lane>>4)*4 + reg
    float* p = part + (size_t)sp * TT * OUTD + (size_t)(mt * 16 + kg * 4) * OUTD + r16;
    #pragma unroll
    for (int j = 0; j < 5; ++j)
        #pragma unroll
        for (int r = 0; r < 4; ++r)
            p[(size_t)r * OUTD + j * 16] = acc[j][r];
}

// ---------------- Kernel 5: split-K reduce + bias ----------------
__global__ __launch_bounds__(256) void k_reduce(const float* __restrict__ part,
                                                const float* __restrict__ bias,
                                                float* __restrict__ out) {
    int idx = blockIdx.x * 256 + threadIdx.x;   // over TT*OUTD = 81920, exact
    int o = idx % OUTD;
    float s = bias[o];
    #pragma unroll
    for (int sp = 0; sp < NSPLIT; ++sp) s += part[(size_t)sp * TT * OUTD + idx];
    out[idx] = s;
}

extern "C" void kernel_launch(void* const* d_in, const int* in_sizes, int n_in,
                              void* d_out, int out_size, void* d_ws, size_t ws_size,
                              hipStream_t stream) {
    const float* feature = (const float*)d_in[0];
    const float* wq      = (const float*)d_in[1];
    const float* wk      = (const float*)d_in[2];
    const float* wv      = (const float*)d_in[3];
    const float* rel_h   = (const float*)d_in[4];
    const float* rel_w   = (const float*)d_in[5];
    const float* dense_w = (const float*)d_in[6];
    const float* dense_b = (const float*)d_in[7];
    float* out = (float*)d_out;

    float*  ws   = (float*)d_ws;
    float*  x    = ws;                                   // TW floats          (1.31 MB)
    ushort* att  = (ushort*)(ws + TW);                   // CC*TW bf16         (13.1 MB)
    ushort* dwb  = att + (size_t)CC * TW;                // OUTD*LIN bf16      (1.02 MB)
    float*  part = (float*)(dwb + (size_t)OUTD * LIN);   // NSPLIT*TT*OUTD f32 (6.55 MB)

    k_pool  <<<TW/256, 256, 0, stream>>>(feature, x);
    k_cvt   <<<(OUTD*LIN)/(256*8), 256, 0, stream>>>(dense_w, dwb);
    k_attn  <<<TW/4/256, 256, 0, stream>>>(x, wq, wk, wv, rel_h, rel_w, att);
    k_gemm  <<<dim3(TT/16, NSPLIT), 64, 0, stream>>>(att, dwb, part);
    k_reduce<<<(TT*OUTD)/256, 256, 0, stream>>>(part, dense_b, out);
}

// Round 3
// 55.415 us; speedup vs baseline: 1.6614x; 1.2190x over previous
//
#include <hip/hip_runtime.h>
#include <hip/hip_bf16.h>

// Problem constants
#define TT   1024            // time steps
#define DD   1280            // feature dim
#define WW   320             // DD / POOL
#define CC   20              // channels
#define HALF 10
#define TW   (TT*WW)         // 327680
#define LIN  (CC*WW)         // 6400  (GEMM K)
#define OUTD 80              // GEMM N
#define NSPLIT 20
#define KCHUNK (LIN/NSPLIT)  // 320
#define KSTEPS (KCHUNK/32)   // 10
#define LOG2E 1.4426950408889634f

typedef __attribute__((ext_vector_type(4))) float f32x4;
typedef __attribute__((ext_vector_type(8))) short bf16x8;

// ---------------- Kernel 1: MaxPool2d((1,4)) ----------------
__global__ __launch_bounds__(256) void k_pool(const float* __restrict__ f,
                                              float* __restrict__ x) {
    int idx = blockIdx.x * 256 + threadIdx.x;          // over TW, exact
    float4 v = reinterpret_cast<const float4*>(f)[idx];
    x[idx] = fmaxf(fmaxf(v.x, v.y), fmaxf(v.z, v.w));
}

// ---------------- Kernel 2: dense_w fp32 -> bf16 ----------------
__global__ __launch_bounds__(256) void k_cvt(const float* __restrict__ dw,
                                             ushort* __restrict__ dwb) {
    int i = (blockIdx.x * 256 + threadIdx.x) * 8;      // 512000/8 = 64000 threads, 250 blocks
    float4 a = reinterpret_cast<const float4*>(dw + i)[0];
    float4 b = reinterpret_cast<const float4*>(dw + i)[1];
    ushort r[8];
    float v[8] = {a.x, a.y, a.z, a.w, b.x, b.y, b.z, b.w};
    #pragma unroll
    for (int j = 0; j < 8; ++j) {
        __hip_bfloat16 h = __float2bfloat16(v[j]);
        r[j] = *reinterpret_cast<ushort*>(&h);
    }
    reinterpret_cast<ushort4*>(dwb + i)[0] = make_ushort4(r[0], r[1], r[2], r[3]);
    reinterpret_cast<ushort4*>(dwb + i)[1] = make_ushort4(r[4], r[5], r[6], r[7]);
}

// ---------------- Kernel 3: 3x3 windowed attention -> bf16 ----------------
// grid: (TW/4/256, 4); blockIdx.y picks a group of 5 channels. Each thread:
// 4 w-positions x 5 channels.
__global__ __launch_bounds__(256) void k_attn(const float* __restrict__ x,
                                              const float* __restrict__ wq,
                                              const float* __restrict__ wk,
                                              const float* __restrict__ wv,
                                              const float* __restrict__ rh,
                                              const float* __restrict__ rw,
                                              ushort* __restrict__ att) {
    __shared__ float s_wqk[CC], s_wr[CC][3], s_wv[CC];
    if (threadIdx.x < CC) {
        int c = threadIdx.x;
        float wqc = wq[c];
        s_wqk[c] = wqc * wk[c] * LOG2E;
        s_wv[c]  = wv[c];
        const float* rp = (c < HALF) ? (rh + c * 3) : (rw + (c - HALF) * 3);
        s_wr[c][0] = wqc * rp[0] * LOG2E;
        s_wr[c][1] = wqc * rp[1] * LOG2E;
        s_wr[c][2] = wqc * rp[2] * LOG2E;
    }
    __syncthreads();

    int idx = blockIdx.x * 256 + threadIdx.x;          // 0..81919
    int t  = idx / (WW / 4);
    int w0 = (idx % (WW / 4)) * 4;
    int c0 = blockIdx.y * 5;                           // channel group (uniform)
    bool ish = (c0 < HALF);                            // block-uniform

    // load x[t-1..t+1][w0-1..w0+4]
    float xr[3][6];
    #pragma unroll
    for (int dt = 0; dt < 3; ++dt) {
        int tt2 = t + dt - 1;
        bool rok = (tt2 >= 0) & (tt2 < TT);
        #pragma unroll
        for (int dw = 0; dw < 6; ++dw) {
            int ww2 = w0 + dw - 1;
            bool ok = rok & (ww2 >= 0) & (ww2 < WW);
            xr[dt][dw] = ok ? x[tt2 * WW + ww2] : 0.0f;
        }
    }

    #pragma unroll
    for (int cc = 0; cc < 5; ++cc) {
        int c = c0 + cc;
        float wqk = s_wqk[c];
        float b0c = s_wr[c][0], b1c = s_wr[c][1], b2c = s_wr[c][2];
        float vv  = s_wv[c];
        ushort res[4];
        #pragma unroll
        for (int p = 0; p < 4; ++p) {
            float xc = xr[1][p + 1];
            float a  = wqk * xc;
            float bb[3] = {xc * b0c, xc * b1c, xc * b2c};
            float s[9];
            #pragma unroll
            for (int dt = 0; dt < 3; ++dt)
                #pragma unroll
                for (int dw = 0; dw < 3; ++dw)
                    s[dt * 3 + dw] = fmaf(a, xr[dt][p + dw], ish ? bb[dt] : bb[dw]);
            float m = fmaxf(fmaxf(fmaxf(s[0], s[1]), fmaxf(s[2], s[3])),
                            fmaxf(fmaxf(s[4], s[5]), fmaxf(fmaxf(s[6], s[7]), s[8])));
            float den = 0.f, num = 0.f;
            #pragma unroll
            for (int dt = 0; dt < 3; ++dt)
                #pragma unroll
                for (int dw = 0; dw < 3; ++dw) {
                    float pp = exp2f(s[dt * 3 + dw] - m);
                    den += pp;
                    num = fmaf(pp, xr[dt][p + dw], num);
                }
            float o = fmaxf(vv * __fdividef(num, den), 0.0f);
            __hip_bfloat16 h = __float2bfloat16(o);
            res[p] = *reinterpret_cast<ushort*>(&h);
        }
        reinterpret_cast<ushort4*>(att + (size_t)c * TW + t * WW + w0)[0] =
            make_ushort4(res[0], res[1], res[2], res[3]);
    }
}

// ---------------- Kernel 4: bf16 MFMA split-K GEMM  [1024 x 6400] * [6400 x 80]^T ----------------
// one wave per block: 16 rows x 80 cols, KCHUNK of K
__global__ __launch_bounds__(64) void k_gemm(const ushort* __restrict__ A,
                                             const ushort* __restrict__ B,
                                             float* __restrict__ part) {
    int lane = threadIdx.x;
    int mt = blockIdx.x;        // 0..63  (M tile of 16 rows)
    int sp = blockIdx.y;        // 0..NSPLIT-1
    int r16 = lane & 15;        // A row / B col / C col
    int kg  = lane >> 4;        // k-group 0..3

    const ushort* ap = A + (size_t)(mt * 16 + r16) * LIN + sp * KCHUNK + kg * 8;
    const ushort* bp = B + (size_t)r16 * LIN + sp * KCHUNK + kg * 8;

    f32x4 acc[5] = {};
    for (int ks = 0; ks < KSTEPS; ++ks) {
        bf16x8 af = *reinterpret_cast<const bf16x8*>(ap);
        #pragma unroll
        for (int j = 0; j < 5; ++j) {
            bf16x8 bfr = *reinterpret_cast<const bf16x8*>(bp + (size_t)j * 16 * LIN);
            acc[j] = __builtin_amdgcn_mfma_f32_16x16x32_bf16(af, bfr, acc[j], 0, 0, 0);
        }
        ap += 32;
        bp += 32;
    }

    // C/D layout: col = lane&15, row = (lane>>4)*4 + reg
    float* p = part + (size_t)sp * TT * OUTD + (size_t)(mt * 16 + kg * 4) * OUTD + r16;
    #pragma unroll
    for (int j = 0; j < 5; ++j)
        #pragma unroll
        for (int r = 0; r < 4; ++r)
            p[(size_t)r * OUTD + j * 16] = acc[j][r];
}

// ---------------- Kernel 5: split-K reduce + bias ----------------
__global__ __launch_bounds__(256) void k_reduce(const float* __restrict__ part,
                                                const float* __restrict__ bias,
                                                float* __restrict__ out) {
    int idx = blockIdx.x * 256 + threadIdx.x;   // over TT*OUTD = 81920, exact
    int o = idx % OUTD;
    float s = bias[o];
    #pragma unroll
    for (int sp = 0; sp < NSPLIT; ++sp) s += part[(size_t)sp * TT * OUTD + idx];
    out[idx] = s;
}

extern "C" void kernel_launch(void* const* d_in, const int* in_sizes, int n_in,
                              void* d_out, int out_size, void* d_ws, size_t ws_size,
                              hipStream_t stream) {
    const float* feature = (const float*)d_in[0];
    const float* wq      = (const float*)d_in[1];
    const float* wk      = (const float*)d_in[2];
    const float* wv      = (const float*)d_in[3];
    const float* rel_h   = (const float*)d_in[4];
    const float* rel_w   = (const float*)d_in[5];
    const float* dense_w = (const float*)d_in[6];
    const float* dense_b = (const float*)d_in[7];
    float* out = (float*)d_out;

    float*  ws   = (float*)d_ws;
    float*  x    = ws;                                   // TW floats          (1.31 MB)
    ushort* att  = (ushort*)(ws + TW);                   // CC*TW bf16         (13.1 MB)
    ushort* dwb  = att + (size_t)CC * TW;                // OUTD*LIN bf16      (1.02 MB)
    float*  part = (float*)(dwb + (size_t)OUTD * LIN);   // NSPLIT*TT*OUTD f32 (6.55 MB)

    k_pool  <<<TW/256, 256, 0, stream>>>(feature, x);
    k_cvt   <<<(OUTD*LIN)/(256*8), 256, 0, stream>>>(dense_w, dwb);
    k_attn  <<<dim3(TW/4/256, 4), 256, 0, stream>>>(x, wq, wk, wv, rel_h, rel_w, att);
    k_gemm  <<<dim3(TT/16, NSPLIT), 64, 0, stream>>>(att, dwb, part);
    k_reduce<<<(TT*OUTD)/256, 256, 0, stream>>>(part, dense_b, out);
}

// Round 4
// 51.877 us; speedup vs baseline: 1.7748x; 1.0682x over previous
//
#include <hip/hip_runtime.h>
#include <hip/hip_bf16.h>

// Problem constants
#define TT   1024            // time steps
#define DD   1280            // feature dim
#define WW   320             // DD / POOL
#define CC   20              // channels
#define HALF 10
#define TW   (TT*WW)         // 327680
#define LIN  (CC*WW)         // 6400  (GEMM K)
#define OUTD 80              // GEMM N
#define NSPLIT 20
#define KCHUNK (LIN/NSPLIT)  // 320
#define KSTEPS (KCHUNK/32)   // 10
#define LOG2E 1.4426950408889634f
#define XPAD 384             // floats of guard on each side of x

typedef __attribute__((ext_vector_type(4))) float f32x4;
typedef __attribute__((ext_vector_type(8))) short bf16x8;

// ---------------- Kernel 1: MaxPool2d((1,4)) ----------------
__global__ __launch_bounds__(256) void k_pool(const float* __restrict__ f,
                                              float* __restrict__ x) {
    int idx = blockIdx.x * 256 + threadIdx.x;          // over TW, exact
    float4 v = reinterpret_cast<const float4*>(f)[idx];
    x[idx] = fmaxf(fmaxf(v.x, v.y), fmaxf(v.z, v.w));
}

// ---------------- Kernel 2: dense_w fp32 -> bf16 ----------------
__global__ __launch_bounds__(256) void k_cvt(const float* __restrict__ dw,
                                             ushort* __restrict__ dwb) {
    int i = (blockIdx.x * 256 + threadIdx.x) * 8;      // 512000/8 = 64000 threads, 250 blocks
    float4 a = reinterpret_cast<const float4*>(dw + i)[0];
    float4 b = reinterpret_cast<const float4*>(dw + i)[1];
    ushort r[8];
    float v[8] = {a.x, a.y, a.z, a.w, b.x, b.y, b.z, b.w};
    #pragma unroll
    for (int j = 0; j < 8; ++j) {
        __hip_bfloat16 h = __float2bfloat16(v[j]);
        r[j] = *reinterpret_cast<ushort*>(&h);
    }
    reinterpret_cast<ushort4*>(dwb + i)[0] = make_ushort4(r[0], r[1], r[2], r[3]);
    reinterpret_cast<ushort4*>(dwb + i)[1] = make_ushort4(r[4], r[5], r[6], r[7]);
}

// ---------------- attention math for 5 channels, ish known at compile time ----------------
template<bool ISH>
__device__ __forceinline__ void attn5(const float xr[3][6],
                                      const float* qk, const float* B0,
                                      const float* B1, const float* B2,
                                      const float* vv, ushort* resall) {
    #pragma unroll
    for (int cc = 0; cc < 5; ++cc) {
        #pragma unroll
        for (int p = 0; p < 4; ++p) {
            float xc = xr[1][p + 1];
            float a  = qk[cc] * xc;
            float b0 = B0[cc] * xc, b1 = B1[cc] * xc, b2 = B2[cc] * xc;
            float s[9];
            #pragma unroll
            for (int dt = 0; dt < 3; ++dt) {
                float bdt = (dt == 0) ? b0 : ((dt == 1) ? b1 : b2);
                #pragma unroll
                for (int dw = 0; dw < 3; ++dw) {
                    float bias = ISH ? bdt : ((dw == 0) ? b0 : ((dw == 1) ? b1 : b2));
                    s[dt * 3 + dw] = fmaf(a, xr[dt][p + dw], bias);
                }
            }
            float m = fmaxf(fmaxf(fmaxf(fmaxf(s[0], s[1]), s[2]),
                                  fmaxf(fmaxf(s[3], s[4]), s[5])),
                            fmaxf(fmaxf(s[6], s[7]), s[8]));
            float den = 0.f, num = 0.f;
            #pragma unroll
            for (int dt = 0; dt < 3; ++dt)
                #pragma unroll
                for (int dw = 0; dw < 3; ++dw) {
                    float e = exp2f(s[dt * 3 + dw] - m);
                    den += e;
                    num = fmaf(e, xr[dt][p + dw], num);
                }
            float o = fmaxf(vv[cc] * __fdividef(num, den), 0.0f);
            __hip_bfloat16 h = __float2bfloat16(o);
            resall[cc * 4 + p] = *reinterpret_cast<ushort*>(&h);
        }
    }
}

// ---------------- Kernel 3: 3x3 windowed attention -> bf16 ----------------
// grid (TW/4/256, 4): blockIdx.y = group of 5 channels; thread = 4 w-positions.
// No LDS: coefficients via uniform (SGPR) loads; x window via float4 loads.
__global__ __launch_bounds__(256, 5) void k_attn(const float* __restrict__ x,
                                                 const float* __restrict__ wq,
                                                 const float* __restrict__ wk,
                                                 const float* __restrict__ wv,
                                                 const float* __restrict__ rh,
                                                 const float* __restrict__ rw,
                                                 ushort* __restrict__ att) {
    int idx = blockIdx.x * 256 + threadIdx.x;          // 0..81919
    int t  = idx / (WW / 4);
    int g  = idx % (WW / 4);
    int w0 = g * 4;
    int c0 = blockIdx.y * 5;                           // block-uniform channel group

    // per-channel coefficients (uniform loads -> SGPR; products in VGPR, once)
    float qk[5], B0[5], B1[5], B2[5], vv5[5];
    #pragma unroll
    for (int cc = 0; cc < 5; ++cc) {
        int c = c0 + cc;
        float wqc = wq[c];
        qk[cc]  = wqc * wk[c] * LOG2E;
        vv5[cc] = wv[c];
        const float* rp = (c < HALF) ? (rh + c * 3) : (rw + (c - HALF) * 3);
        B0[cc] = wqc * rp[0] * LOG2E;
        B1[cc] = wqc * rp[1] * LOG2E;
        B2[cc] = wqc * rp[2] * LOG2E;
    }

    // x[t-1..t+1][w0-1..w0+4] via 2x float4 + 1 scalar per row (guard pads keep OOB mapped)
    float xr[3][6];
    const float* xb = x + t * WW + w0;
    #pragma unroll
    for (int dt = 0; dt < 3; ++dt) {
        const float* rp = xb + (dt - 1) * WW;
        float4 va = *reinterpret_cast<const float4*>(rp - 4);
        float4 vb = *reinterpret_cast<const float4*>(rp);
        float  vc = rp[4];
        int tt2 = t + dt - 1;
        bool rok = (tt2 >= 0) & (tt2 < TT);
        xr[dt][0] = (rok & (g > 0))  ? va.w : 0.f;
        xr[dt][1] = rok ? vb.x : 0.f;
        xr[dt][2] = rok ? vb.y : 0.f;
        xr[dt][3] = rok ? vb.z : 0.f;
        xr[dt][4] = rok ? vb.w : 0.f;
        xr[dt][5] = (rok & (g < 79)) ? vc : 0.f;
    }

    ushort4 res4[5];
    if (c0 < HALF) attn5<true >(xr, qk, B0, B1, B2, vv5, reinterpret_cast<ushort*>(res4));
    else           attn5<false>(xr, qk, B0, B1, B2, vv5, reinterpret_cast<ushort*>(res4));

    #pragma unroll
    for (int cc = 0; cc < 5; ++cc)
        reinterpret_cast<ushort4*>(att + (size_t)(c0 + cc) * TW + t * WW + w0)[0] = res4[cc];
}

// ---------------- Kernel 4: bf16 MFMA split-K GEMM  [1024 x 6400] * [6400 x 80]^T ----------------
// one wave per block: 16 rows x 80 cols, KCHUNK of K
__global__ __launch_bounds__(64) void k_gemm(const ushort* __restrict__ A,
                                             const ushort* __restrict__ B,
                                             float* __restrict__ part) {
    int lane = threadIdx.x;
    int mt = blockIdx.x;        // 0..63  (M tile of 16 rows)
    int sp = blockIdx.y;        // 0..NSPLIT-1
    int r16 = lane & 15;        // A row / B col / C col
    int kg  = lane >> 4;        // k-group 0..3

    const ushort* ap = A + (size_t)(mt * 16 + r16) * LIN + sp * KCHUNK + kg * 8;
    const ushort* bp = B + (size_t)r16 * LIN + sp * KCHUNK + kg * 8;

    f32x4 acc[5] = {};
    for (int ks = 0; ks < KSTEPS; ++ks) {
        bf16x8 af = *reinterpret_cast<const bf16x8*>(ap);
        #pragma unroll
        for (int j = 0; j < 5; ++j) {
            bf16x8 bfr = *reinterpret_cast<const bf16x8*>(bp + (size_t)j * 16 * LIN);
            acc[j] = __builtin_amdgcn_mfma_f32_16x16x32_bf16(af, bfr, acc[j], 0, 0, 0);
        }
        ap += 32;
        bp += 32;
    }

    // C/D layout: col = lane&15, row = (lane>>4)*4 + reg
    float* p = part + (size_t)sp * TT * OUTD + (size_t)(mt * 16 + kg * 4) * OUTD + r16;
    #pragma unroll
    for (int j = 0; j < 5; ++j)
        #pragma unroll
        for (int r = 0; r < 4; ++r)
            p[(size_t)r * OUTD + j * 16] = acc[j][r];
}

// ---------------- Kernel 5: split-K reduce + bias ----------------
__global__ __launch_bounds__(256) void k_reduce(const float* __restrict__ part,
                                                const float* __restrict__ bias,
                                                float* __restrict__ out) {
    int idx = blockIdx.x * 256 + threadIdx.x;   // over TT*OUTD = 81920, exact
    int o = idx % OUTD;
    float s = bias[o];
    #pragma unroll
    for (int sp = 0; sp < NSPLIT; ++sp) s += part[(size_t)sp * TT * OUTD + idx];
    out[idx] = s;
}

extern "C" void kernel_launch(void* const* d_in, const int* in_sizes, int n_in,
                              void* d_out, int out_size, void* d_ws, size_t ws_size,
                              hipStream_t stream) {
    const float* feature = (const float*)d_in[0];
    const float* wq      = (const float*)d_in[1];
    const float* wk      = (const float*)d_in[2];
    const float* wv      = (const float*)d_in[3];
    const float* rel_h   = (const float*)d_in[4];
    const float* rel_w   = (const float*)d_in[5];
    const float* dense_w = (const float*)d_in[6];
    const float* dense_b = (const float*)d_in[7];
    float* out = (float*)d_out;

    float*  ws   = (float*)d_ws;
    float*  x    = ws + XPAD;                            // TW floats, guarded both sides
    ushort* att  = (ushort*)(ws + 2 * XPAD + TW);        // CC*TW bf16         (13.1 MB)
    ushort* dwb  = att + (size_t)CC * TW;                // OUTD*LIN bf16      (1.02 MB)
    float*  part = (float*)(dwb + (size_t)OUTD * LIN);   // NSPLIT*TT*OUTD f32 (6.55 MB)

    k_pool  <<<TW/256, 256, 0, stream>>>(feature, x);
    k_cvt   <<<(OUTD*LIN)/(256*8), 256, 0, stream>>>(dense_w, dwb);
    k_attn  <<<dim3(TW/4/256, 4), 256, 0, stream>>>(x, wq, wk, wv, rel_h, rel_w, att);
    k_gemm  <<<dim3(TT/16, NSPLIT), 64, 0, stream>>>(att, dwb, part);
    k_reduce<<<(TT*OUTD)/256, 256, 0, stream>>>(part, dense_b, out);
}

// Round 5
// 42.398 us; speedup vs baseline: 2.1715x; 1.2236x over previous
//
#include <hip/hip_runtime.h>
#include <hip/hip_bf16.h>

// Problem constants
#define TT   1024            // time steps
#define DD   1280            // feature dim
#define WW   320             // DD / POOL
#define CC   20              // channels
#define HALF 10
#define TW   (TT*WW)         // 327680
#define LIN  (CC*WW)         // 6400  (GEMM K)
#define OUTD 80              // GEMM N
#define NSPLIT 20
#define KCHUNK (LIN/NSPLIT)  // 320
#define KSTEPS (KCHUNK/32)   // 10
#define LOG2E 1.4426950408889634f
#define XPAD 384             // floats of guard on each side of x

#define POOL_BLOCKS (TW/256)           // 1280
#define CVT_BLOCKS  ((OUTD*LIN)/(256*8)) // 250

typedef __attribute__((ext_vector_type(4))) float f32x4;
typedef __attribute__((ext_vector_type(8))) short bf16x8;

// RNE float->bf16, finite values only (no NaN path)
__device__ __forceinline__ ushort f2bf(float v) {
    unsigned u = __float_as_uint(v);
    u += 0x7FFFu + ((u >> 16) & 1u);
    return (ushort)(u >> 16);
}

// ---------------- Kernel 1: MaxPool2d((1,4))  +  dense_w fp32->bf16 ----------------
__global__ __launch_bounds__(256) void k_prep(const float* __restrict__ f,
                                              float* __restrict__ x,
                                              const float* __restrict__ dw,
                                              ushort* __restrict__ dwb) {
    int b = blockIdx.x;
    if (b < POOL_BLOCKS) {
        int idx = b * 256 + threadIdx.x;               // over TW, exact
        float4 v = reinterpret_cast<const float4*>(f)[idx];
        x[idx] = fmaxf(fmaxf(v.x, v.y), fmaxf(v.z, v.w));
    } else {
        int i = ((b - POOL_BLOCKS) * 256 + threadIdx.x) * 8;
        float4 a = reinterpret_cast<const float4*>(dw + i)[0];
        float4 c = reinterpret_cast<const float4*>(dw + i)[1];
        reinterpret_cast<ushort4*>(dwb + i)[0] =
            make_ushort4(f2bf(a.x), f2bf(a.y), f2bf(a.z), f2bf(a.w));
        reinterpret_cast<ushort4*>(dwb + i)[1] =
            make_ushort4(f2bf(c.x), f2bf(c.y), f2bf(c.z), f2bf(c.w));
    }
}

// ---------------- attention math for 5 channels, ish known at compile time ----------------
template<bool ISH>
__device__ __forceinline__ void attn5(const float xr[3][6],
                                      const float* qk, const float* B0,
                                      const float* B1, const float* B2,
                                      const float* vv, ushort* resall) {
    #pragma unroll
    for (int cc = 0; cc < 5; ++cc) {
        #pragma unroll
        for (int p = 0; p < 4; ++p) {
            float xc = xr[1][p + 1];
            float a  = qk[cc] * xc;
            float b0 = B0[cc] * xc, b1 = B1[cc] * xc, b2 = B2[cc] * xc;
            float s[9];
            #pragma unroll
            for (int dt = 0; dt < 3; ++dt) {
                float bdt = (dt == 0) ? b0 : ((dt == 1) ? b1 : b2);
                #pragma unroll
                for (int dw = 0; dw < 3; ++dw) {
                    float bias = ISH ? bdt : ((dw == 0) ? b0 : ((dw == 1) ? b1 : b2));
                    s[dt * 3 + dw] = fmaf(a, xr[dt][p + dw], bias);
                }
            }
            float m = fmaxf(fmaxf(fmaxf(fmaxf(s[0], s[1]), s[2]),
                                  fmaxf(fmaxf(s[3], s[4]), s[5])),
                            fmaxf(fmaxf(s[6], s[7]), s[8]));
            float den = 0.f, num = 0.f;
            #pragma unroll
            for (int dt = 0; dt < 3; ++dt)
                #pragma unroll
                for (int dw = 0; dw < 3; ++dw) {
                    float e = __builtin_amdgcn_exp2f(s[dt * 3 + dw] - m);
                    den += e;
                    num = fmaf(e, xr[dt][p + dw], num);
                }
            float o = fmaxf(vv[cc] * (num * __builtin_amdgcn_rcpf(den)), 0.0f);
            resall[cc * 4 + p] = f2bf(o);
        }
    }
}

// ---------------- Kernel 2: 3x3 windowed attention -> bf16 ----------------
// grid (TW/4/256, 4): blockIdx.y = group of 5 channels; thread = 4 w-positions.
__global__ __launch_bounds__(256, 5) void k_attn(const float* __restrict__ x,
                                                 const float* __restrict__ wq,
                                                 const float* __restrict__ wk,
                                                 const float* __restrict__ wv,
                                                 const float* __restrict__ rh,
                                                 const float* __restrict__ rw,
                                                 ushort* __restrict__ att) {
    int idx = blockIdx.x * 256 + threadIdx.x;          // 0..81919
    int t  = idx / (WW / 4);
    int g  = idx % (WW / 4);
    int w0 = g * 4;
    int c0 = blockIdx.y * 5;                           // block-uniform channel group

    // per-channel coefficients (uniform loads; products computed once)
    float qk[5], B0[5], B1[5], B2[5], vv5[5];
    #pragma unroll
    for (int cc = 0; cc < 5; ++cc) {
        int c = c0 + cc;
        float wqc = wq[c];
        qk[cc]  = wqc * wk[c] * LOG2E;
        vv5[cc] = wv[c];
        const float* rp = (c < HALF) ? (rh + c * 3) : (rw + (c - HALF) * 3);
        B0[cc] = wqc * rp[0] * LOG2E;
        B1[cc] = wqc * rp[1] * LOG2E;
        B2[cc] = wqc * rp[2] * LOG2E;
    }

    // x[t-1..t+1][w0-1..w0+4] via 2x float4 + 1 scalar per row (guard pads keep OOB mapped)
    float xr[3][6];
    const float* xb = x + t * WW + w0;
    #pragma unroll
    for (int dt = 0; dt < 3; ++dt) {
        const float* rp = xb + (dt - 1) * WW;
        float4 va = *reinterpret_cast<const float4*>(rp - 4);
        float4 vb = *reinterpret_cast<const float4*>(rp);
        float  vc = rp[4];
        int tt2 = t + dt - 1;
        bool rok = (tt2 >= 0) & (tt2 < TT);
        xr[dt][0] = (rok & (g > 0))  ? va.w : 0.f;
        xr[dt][1] = rok ? vb.x : 0.f;
        xr[dt][2] = rok ? vb.y : 0.f;
        xr[dt][3] = rok ? vb.z : 0.f;
        xr[dt][4] = rok ? vb.w : 0.f;
        xr[dt][5] = (rok & (g < 79)) ? vc : 0.f;
    }

    ushort4 res4[5];
    if (c0 < HALF) attn5<true >(xr, qk, B0, B1, B2, vv5, reinterpret_cast<ushort*>(res4));
    else           attn5<false>(xr, qk, B0, B1, B2, vv5, reinterpret_cast<ushort*>(res4));

    #pragma unroll
    for (int cc = 0; cc < 5; ++cc)
        reinterpret_cast<ushort4*>(att + (size_t)(c0 + cc) * TW + t * WW + w0)[0] = res4[cc];
}

// ---------------- Kernel 3: bf16 MFMA split-K GEMM  [1024 x 6400] * [6400 x 80]^T ----------------
// one wave per block: 16 rows x 80 cols, KCHUNK of K
__global__ __launch_bounds__(64) void k_gemm(const ushort* __restrict__ A,
                                             const ushort* __restrict__ B,
                                             float* __restrict__ part) {
    int lane = threadIdx.x;
    int mt = blockIdx.x;        // 0..63  (M tile of 16 rows)
    int sp = blockIdx.y;        // 0..NSPLIT-1
    int r16 = lane & 15;        // A row / B col / C col
    int kg  = lane >> 4;        // k-group 0..3

    const ushort* ap = A + (size_t)(mt * 16 + r16) * LIN + sp * KCHUNK + kg * 8;
    const ushort* bp = B + (size_t)r16 * LIN + sp * KCHUNK + kg * 8;

    f32x4 acc[5] = {};
    for (int ks = 0; ks < KSTEPS; ++ks) {
        bf16x8 af = *reinterpret_cast<const bf16x8*>(ap);
        #pragma unroll
        for (int j = 0; j < 5; ++j) {
            bf16x8 bfr = *reinterpret_cast<const bf16x8*>(bp + (size_t)j * 16 * LIN);
            acc[j] = __builtin_amdgcn_mfma_f32_16x16x32_bf16(af, bfr, acc[j], 0, 0, 0);
        }
        ap += 32;
        bp += 32;
    }

    // C/D layout: col = lane&15, row = (lane>>4)*4 + reg
    float* p = part + (size_t)sp * TT * OUTD + (size_t)(mt * 16 + kg * 4) * OUTD + r16;
    #pragma unroll
    for (int j = 0; j < 5; ++j)
        #pragma unroll
        for (int r = 0; r < 4; ++r)
            p[(size_t)r * OUTD + j * 16] = acc[j][r];
}

// ---------------- Kernel 4: split-K reduce + bias ----------------
__global__ __launch_bounds__(256) void k_reduce(const float* __restrict__ part,
                                                const float* __restrict__ bias,
                                                float* __restrict__ out) {
    int idx = blockIdx.x * 256 + threadIdx.x;   // over TT*OUTD = 81920, exact
    int o = idx % OUTD;
    float s = bias[o];
    #pragma unroll
    for (int sp = 0; sp < NSPLIT; ++sp) s += part[(size_t)sp * TT * OUTD + idx];
    out[idx] = s;
}

extern "C" void kernel_launch(void* const* d_in, const int* in_sizes, int n_in,
                              void* d_out, int out_size, void* d_ws, size_t ws_size,
                              hipStream_t stream) {
    const float* feature = (const float*)d_in[0];
    const float* wq      = (const float*)d_in[1];
    const float* wk      = (const float*)d_in[2];
    const float* wv      = (const float*)d_in[3];
    const float* rel_h   = (const float*)d_in[4];
    const float* rel_w   = (const float*)d_in[5];
    const float* dense_w = (const float*)d_in[6];
    const float* dense_b = (const float*)d_in[7];
    float* out = (float*)d_out;

    float*  ws   = (float*)d_ws;
    float*  x    = ws + XPAD;                            // TW floats, guarded both sides
    ushort* att  = (ushort*)(ws + 2 * XPAD + TW);        // CC*TW bf16         (13.1 MB)
    ushort* dwb  = att + (size_t)CC * TW;                // OUTD*LIN bf16      (1.02 MB)
    float*  part = (float*)(dwb + (size_t)OUTD * LIN);   // NSPLIT*TT*OUTD f32 (6.55 MB)

    k_prep  <<<POOL_BLOCKS + CVT_BLOCKS, 256, 0, stream>>>(feature, x, dense_w, dwb);
    k_attn  <<<dim3(TW/4/256, 4), 256, 0, stream>>>(x, wq, wk, wv, rel_h, rel_w, att);
    k_gemm  <<<dim3(TT/16, NSPLIT), 64, 0, stream>>>(att, dwb, part);
    k_reduce<<<(TT*OUTD)/256, 256, 0, stream>>>(part, dense_b, out);
}